// Round 1
// baseline (66.074 us; speedup 1.0000x reference)
//
#include <hip/hip_runtime.h>

// MLP: 30->24->19->14->10->6->2->1, ReLU between all but last layer.
// One thread per row. Weights staged in LDS, rows padded to multiples of
// 4 floats so weight reads are 16B-aligned ds_read_b128 broadcasts.

// Padded LDS layout (floats):
//  W1 @    0  : 24 rows x 32  = 768
//  W2 @  768  : 19 rows x 24  = 456
//  W3 @ 1224  : 14 rows x 20  = 280
//  W4 @ 1504  : 10 rows x 16  = 160
//  W5 @ 1664  :  6 rows x 12  =  72
//  W6 @ 1736  :  2 rows x  8  =  16
//  W7 @ 1752  :  1 row  x  4  =   4
//  b1 @ 1756 (24), b2 @ 1780 (19), b3 @ 1799 (14), b4 @ 1813 (10),
//  b5 @ 1823 (6), b6 @ 1829 (2), b7 @ 1831 (1)  -> total 1832 floats (7328 B)

#define NTHREADS 256

template <int FIN, int PAD, int FOUT>
__device__ __forceinline__ void stage_w(const float* __restrict__ g, float* __restrict__ s, int t) {
    for (int idx = t; idx < FOUT * PAD; idx += NTHREADS) {
        int r = idx / PAD;
        int c = idx - r * PAD;
        s[idx] = (c < FIN) ? g[r * FIN + c] : 0.0f;
    }
}

template <int FIN, int PAD, int FOUT, bool RELU>
__device__ __forceinline__ void layer(const float* __restrict__ wl, const float* __restrict__ bl,
                                      const float* __restrict__ in, float* __restrict__ outv) {
#pragma unroll
    for (int j = 0; j < FOUT; ++j) {
        float acc = bl[j];
        const float4* wr = (const float4*)(wl + j * PAD);
#pragma unroll
        for (int k4 = 0; k4 < PAD / 4; ++k4) {
            float4 w4 = wr[k4];
            if (4 * k4 + 0 < FIN) acc = fmaf(w4.x, in[4 * k4 + 0], acc);
            if (4 * k4 + 1 < FIN) acc = fmaf(w4.y, in[4 * k4 + 1], acc);
            if (4 * k4 + 2 < FIN) acc = fmaf(w4.z, in[4 * k4 + 2], acc);
            if (4 * k4 + 3 < FIN) acc = fmaf(w4.w, in[4 * k4 + 3], acc);
        }
        outv[j] = RELU ? fmaxf(acc, 0.0f) : acc;
    }
}

__global__ __launch_bounds__(NTHREADS) void mlp_fused(
    const float* __restrict__ x,
    const float* __restrict__ W1, const float* __restrict__ B1,
    const float* __restrict__ W2, const float* __restrict__ B2,
    const float* __restrict__ W3, const float* __restrict__ B3,
    const float* __restrict__ W4, const float* __restrict__ B4,
    const float* __restrict__ W5, const float* __restrict__ B5,
    const float* __restrict__ W6, const float* __restrict__ B6,
    const float* __restrict__ W7, const float* __restrict__ B7,
    float* __restrict__ out, int nrows)
{
    __shared__ float s[1832];
    const int t = threadIdx.x;

    stage_w<30, 32, 24>(W1, s + 0,    t);
    stage_w<24, 24, 19>(W2, s + 768,  t);
    stage_w<19, 20, 14>(W3, s + 1224, t);
    stage_w<14, 16, 10>(W4, s + 1504, t);
    stage_w<10, 12, 6 >(W5, s + 1664, t);
    stage_w<6,  8,  2 >(W6, s + 1736, t);
    stage_w<2,  4,  1 >(W7, s + 1752, t);
    if (t < 24) s[1756 + t] = B1[t];
    if (t < 19) s[1780 + t] = B2[t];
    if (t < 14) s[1799 + t] = B3[t];
    if (t < 10) s[1813 + t] = B4[t];
    if (t < 6)  s[1823 + t] = B5[t];
    if (t < 2)  s[1829 + t] = B6[t];
    if (t < 1)  s[1831 + t] = B7[t];
    __syncthreads();

    int row = blockIdx.x * NTHREADS + t;
    if (row >= nrows) return;

    // Load the 30 input features. Row base = row*120 B (8B aligned) -> float2.
    float xr[30];
    const float2* xp = (const float2*)(x + (size_t)row * 30);
#pragma unroll
    for (int i = 0; i < 15; ++i) {
        float2 v = xp[i];
        xr[2 * i + 0] = v.x;
        xr[2 * i + 1] = v.y;
    }

    float h1[24]; layer<30, 32, 24, true >(s + 0,    s + 1756, xr, h1);
    float h2[19]; layer<24, 24, 19, true >(s + 768,  s + 1780, h1, h2);
    float h3[14]; layer<19, 20, 14, true >(s + 1224, s + 1799, h2, h3);
    float h4[10]; layer<14, 16, 10, true >(s + 1504, s + 1813, h3, h4);
    float h5[6];  layer<10, 12, 6,  true >(s + 1664, s + 1823, h4, h5);
    float h6[2];  layer<6,  8,  2,  true >(s + 1736, s + 1829, h5, h6);
    float h7[1];  layer<2,  4,  1,  false>(s + 1752, s + 1831, h6, h7);

    out[row] = h7[0];
}

extern "C" void kernel_launch(void* const* d_in, const int* in_sizes, int n_in,
                              void* d_out, int out_size, void* d_ws, size_t ws_size,
                              hipStream_t stream) {
    const float* x = (const float*)d_in[0];
    int nrows = in_sizes[0] / 30;
    int blocks = (nrows + NTHREADS - 1) / NTHREADS;
    mlp_fused<<<blocks, NTHREADS, 0, stream>>>(
        x,
        (const float*)d_in[1],  (const float*)d_in[2],
        (const float*)d_in[3],  (const float*)d_in[4],
        (const float*)d_in[5],  (const float*)d_in[6],
        (const float*)d_in[7],  (const float*)d_in[8],
        (const float*)d_in[9],  (const float*)d_in[10],
        (const float*)d_in[11], (const float*)d_in[12],
        (const float*)d_in[13], (const float*)d_in[14],
        (float*)d_out, nrows);
}